// Round 6
// baseline (525.629 us; speedup 1.0000x reference)
//
#include <hip/hip_runtime.h>

// Problem constants
#define NN 50000
#define EE 800000
#define FF 256   // IN = HID = PROJ = 256
#define NBLK 196 // ceil(NN/256)

typedef float    f32x4 __attribute__((ext_vector_type(4)));
typedef _Float16 f16x8 __attribute__((ext_vector_type(8)));
typedef _Float16 f16x4 __attribute__((ext_vector_type(4)));

// ---------------------------------------------------------------------------
// CSR build kernels (unchanged)
// ---------------------------------------------------------------------------

__global__ void count_kernel(const int* __restrict__ ei, int* __restrict__ ec) {
    int e = blockIdx.x * 256 + threadIdx.x;
    if (e < EE) atomicAdd(&ec[ei[EE + e]], 1);
}

__global__ __launch_bounds__(256) void scan_part(const int* __restrict__ ec,
                                                 int* __restrict__ bsum) {
    int i = blockIdx.x * 256 + threadIdx.x;
    int v = (i < NN) ? ec[i] : 0;
#pragma unroll
    for (int d = 1; d < 64; d <<= 1) v += __shfl_xor(v, d);
    __shared__ int wt[4];
    int lane = threadIdx.x & 63, wid = threadIdx.x >> 6;
    if (lane == 0) wt[wid] = v;
    __syncthreads();
    if (threadIdx.x == 0)
        bsum[blockIdx.x] = wt[0] + wt[1] + wt[2] + wt[3];
}

__global__ __launch_bounds__(256) void scan_mid(const int* __restrict__ bsum,
                                                int* __restrict__ boff,
                                                int* __restrict__ rs) {
    const int t = threadIdx.x;
    int v = (t < NBLK) ? bsum[t] : 0;
    int lane = t & 63, wid = t >> 6;
    int x = v;
#pragma unroll
    for (int d = 1; d < 64; d <<= 1) {
        int u = __shfl_up(x, d);
        if (lane >= d) x += u;
    }
    __shared__ int wt[4];
    if (lane == 63) wt[wid] = x;
    __syncthreads();
    int add = 0;
    for (int wi = 0; wi < wid; ++wi) add += wt[wi];
    x += add;                                   // inclusive scan
    if (t < NBLK) boff[t] = x - v;              // exclusive
    if (t == NBLK - 1) rs[NN] = x;              // total == EE
}

__global__ __launch_bounds__(256) void scan_final(const int* __restrict__ ec,
                                                  const int* __restrict__ boff,
                                                  int* __restrict__ rs,
                                                  float* __restrict__ dinv) {
    int i = blockIdx.x * 256 + threadIdx.x;
    int v = (i < NN) ? ec[i] : 0;
    int lane = threadIdx.x & 63, wid = threadIdx.x >> 6;
    int x = v;
#pragma unroll
    for (int d = 1; d < 64; d <<= 1) {
        int u = __shfl_up(x, d);
        if (lane >= d) x += u;
    }
    __shared__ int wt[4];
    if (lane == 63) wt[wid] = x;
    __syncthreads();
    int add = 0;
    for (int wi = 0; wi < wid; ++wi) add += wt[wi];
    x += add;                                   // block-inclusive
    if (i < NN) {
        rs[i]   = x - v + boff[blockIdx.x];     // global exclusive
        dinv[i] = rsqrtf((float)(v + 1));       // deg = edges + self-loop
    }
}

__global__ void fill_kernel(const int* __restrict__ ei, const int* __restrict__ rs,
                            int* __restrict__ cnt, const float* __restrict__ dinv,
                            int2* __restrict__ ecw) {
    int e = blockIdx.x * 256 + threadIdx.x;
    if (e >= EE) return;
    int s = ei[e];
    int d = ei[EE + e];
    int p = rs[d] + atomicAdd(&cnt[d], 1);
    ecw[p] = make_int2(s, __float_as_int(dinv[s]));
}

// ---------------------------------------------------------------------------
// W pack: swizzled LDS-image (unchanged)
// ---------------------------------------------------------------------------
__global__ void packw_kernel(const float* __restrict__ W1, const float* __restrict__ W2,
                             _Float16* __restrict__ wp) {
    int idx = blockIdx.x * 256 + threadIdx.x;   // 0..16383
    int p   = idx & 511;
    int kt  = (idx >> 9) & 7;
    int nb  = (idx >> 12) & 1;
    int L   = (idx >> 13) & 1;
    const float* W = L ? W2 : W1;
    int rs = p >> 2, cs = p & 3;
    int r  = rs ^ ((rs >> 2) & 1);
    int c  = cs ^ (r & 3);
    int n  = nb * 128 + r;
    int k0 = kt * 32 + c * 8;
    f16x8 hi, lo;
#pragma unroll
    for (int j = 0; j < 8; ++j) {
        float v = W[(size_t)(k0 + j) * 256 + n];
        _Float16 h = (_Float16)v;
        hi[j] = h;
        lo[j] = (_Float16)(v - (float)h);
    }
    size_t ch = ((size_t)((L * 2 + 0) * 2 + nb) * 8 + kt) * 4096;
    size_t cl = ((size_t)((L * 2 + 1) * 2 + nb) * 8 + kt) * 4096;
    *(f16x8*)(wp + ch + (size_t)p * 8) = hi;
    *(f16x8*)(wp + cl + (size_t)p * 8) = lo;
}

// ---------------------------------------------------------------------------
// GEMM (unchanged from round 4). Output H is SLICE-MAJOR: Hs[slice][row][32].
// ---------------------------------------------------------------------------

__device__ __forceinline__ void gll16(const void* g, void* l) {
    __builtin_amdgcn_global_load_lds(
        (const __attribute__((address_space(1))) void*)g,
        (__attribute__((address_space(3))) void*)l, 16, 0, 0);
}

template<typename AT>
__global__ __launch_bounds__(512) void gemm_kernel(
    const AT* __restrict__ X, const _Float16* __restrict__ Bhi,
    const _Float16* __restrict__ Blo, _Float16* __restrict__ H) {
    __shared__ __align__(16) _Float16 Bh[2][4096];   // 2 x 8KB
    __shared__ __align__(16) _Float16 Bl[2][4096];   // 2 x 8KB
    __shared__ __align__(16) AT       As[2][4096];   // fp32: 2x16KB, fp16: 2x8KB

    const int gid = blockIdx.x;
    const int p_  = (gid >> 4) * 8 + (gid & 7);
    const int nb  = (gid >> 3) & 1;
    if (p_ >= 391) return;

    const int tid = threadIdx.x;
    const int ln  = tid & 63;
    const int w   = tid >> 6;        // 0..7
    const int wm  = w & 1;           // 2 x 64 rows
    const int wn  = w >> 1;          // 4 x 32 cols
    const int q   = ln >> 4;         // k-group
    const int l16 = ln & 15;
    const int m0  = p_ * 128;
    const size_t bchunk = (size_t)nb * 8 * 4096;

    f32x4 acc[4][2] = {};            // [mt][nt]

    auto stage = [&](int kt, int buf) {
        int g = w * 64 + ln;                       // granule 0..511
        gll16(Bhi + bchunk + (size_t)kt * 4096 + (size_t)g * 8,
              &Bh[buf][w * 512]);
        gll16(Blo + bchunk + (size_t)kt * 4096 + (size_t)g * 8,
              &Bl[buf][w * 512]);
        if constexpr (sizeof(AT) == 4) {
#pragma unroll
            for (int pp = 0; pp < 2; ++pp) {
                int gg = pp * 512 + w * 64 + ln;    // 0..1023
                int rss = gg >> 3, cs = gg & 7;
                int c  = cs ^ (rss & 7);
                int gm = m0 + rss; if (gm > NN - 1) gm = NN - 1;
                gll16((const float*)X + (size_t)gm * FF + kt * 32 + c * 4,
                      (float*)&As[buf][0] + (size_t)(pp * 512 + w * 64) * 4);
            }
        } else {
            int rss = g >> 2, cs = g & 3;
            int r  = rss ^ ((rss >> 2) & 1);
            int c  = cs ^ (r & 3);
            int gm = m0 + r; if (gm > NN - 1) gm = NN - 1;
            gll16((const _Float16*)X + ((size_t)kt * NN + gm) * 32 + c * 8,
                  (_Float16*)&As[buf][0] + (size_t)(w * 64) * 8);
        }
    };

    auto compute = [&](int buf) {
        f16x8 af[4], bhf[2], blf[2];
#pragma unroll
        for (int mt = 0; mt < 4; ++mt) {
            int r = wm * 64 + mt * 16 + l16;
            if constexpr (sizeof(AT) == 4) {
                const float* Ab = (const float*)&As[buf][0];
                f32x4 v0 = *(const f32x4*)(Ab + (size_t)(r * 8 + ((2 * q)     ^ (r & 7))) * 4);
                f32x4 v1 = *(const f32x4*)(Ab + (size_t)(r * 8 + ((2 * q + 1) ^ (r & 7))) * 4);
                f16x8 a;
                a[0] = (_Float16)v0.x; a[1] = (_Float16)v0.y;
                a[2] = (_Float16)v0.z; a[3] = (_Float16)v0.w;
                a[4] = (_Float16)v1.x; a[5] = (_Float16)v1.y;
                a[6] = (_Float16)v1.z; a[7] = (_Float16)v1.w;
                af[mt] = a;
            } else {
                const _Float16* Ab = (const _Float16*)&As[buf][0];
                int rr = r ^ ((r >> 2) & 1);
                af[mt] = *(const f16x8*)(Ab + (size_t)(rr * 4 + (q ^ (r & 3))) * 8);
            }
        }
#pragma unroll
        for (int nt = 0; nt < 2; ++nt) {
            int r  = wn * 32 + nt * 16 + l16;
            int rr = r ^ ((r >> 2) & 1);
            int off = (rr * 4 + (q ^ (r & 3))) * 8;
            bhf[nt] = *(const f16x8*)(&Bh[buf][off]);
            blf[nt] = *(const f16x8*)(&Bl[buf][off]);
        }
#pragma unroll
        for (int mt = 0; mt < 4; ++mt)
#pragma unroll
            for (int nt = 0; nt < 2; ++nt) {
                acc[mt][nt] = __builtin_amdgcn_mfma_f32_16x16x32_f16(af[mt], bhf[nt], acc[mt][nt], 0, 0, 0);
                acc[mt][nt] = __builtin_amdgcn_mfma_f32_16x16x32_f16(af[mt], blf[nt], acc[mt][nt], 0, 0, 0);
            }
    };

    stage(0, 0);
    __syncthreads();
    int cur = 0;
#pragma unroll
    for (int kt = 0; kt < 8; ++kt) {
        if (kt < 7) stage(kt + 1, cur ^ 1);
        compute(cur);
        __syncthreads();
        cur ^= 1;
    }

    const int sl = nb * 4 + wn;
#pragma unroll
    for (int mt = 0; mt < 4; ++mt)
#pragma unroll
        for (int r4 = 0; r4 < 4; ++r4) {
            int m = m0 + wm * 64 + mt * 16 + q * 4 + r4;
            if (m < NN) {
#pragma unroll
                for (int nt = 0; nt < 2; ++nt) {
                    H[((size_t)sl * NN + m) * 32 + nt * 16 + l16] =
                        (_Float16)acc[mt][nt][r4];
                }
            }
        }
}

// ---------------------------------------------------------------------------
// Aggregation + bias + PReLU: XCD-resident slicing + pure-TLP gather.
// H slice-major [8][NN][32] fp16 (3.2 MB/slice, L2-resident per XCD;
// slice = blockIdx & 7 under round-robin dispatch -- proven in round 4:
// FETCH dropped to 40 MB).
// One WAVE = one (row, slice) task. Lane = edge-slot (lane>>2, 16 slots) x
// 16B feature piece (lane&3): 16 edges in flight per wave, 2x unrolled -> 32.
// No barriers, no LDS, no inline asm: latency hidden by TLP (32 waves/CU,
// 400K independent wave-tasks). Records loaded cached (one 128B line per
// row, LLC-shared across the 8 XCDs reading it concurrently). Final reduce:
// 4-step shfl_xor across edge-slots. NT stores only for fp32 final output.
// ---------------------------------------------------------------------------
template<typename OT>
__global__ __launch_bounds__(256) void agg_kernel(
    const _Float16* __restrict__ Hs, const int* __restrict__ rs,
    const int2* __restrict__ ecw, const float* __restrict__ dinv,
    const float* __restrict__ bias, const float* __restrict__ a_ptr,
    OT* __restrict__ out) {
    const int slice = blockIdx.x & 7;
    const int wv    = threadIdx.x >> 6;            // wave 0..3
    const int row   = (blockIdx.x >> 3) * 4 + wv;  // < NN (12500*4 == 50000)
    const int lane  = threadIdx.x & 63;
    const int es    = lane >> 2;                   // edge slot 0..15
    const int f     = lane & 3;                    // 16B feature piece 0..3

    const _Float16* Hsl = Hs + (size_t)slice * ((size_t)NN * 32);
    const float av = a_ptr[0];
    const float di = dinv[row];
    const int erow = rs[row];
    const int eend = rs[row + 1];

    // accumulators: 8 features (this lane's 16B piece)
    float a0, a1, a2, a3, a4, a5, a6, a7;
    {   // self-loop term, counted once (slot 0)
        f16x8 hv = *(const f16x8*)(Hsl + (size_t)row * 32 + f * 8);
        float m = (es == 0) ? di : 0.f;
        a0 = m * (float)hv[0]; a1 = m * (float)hv[1];
        a2 = m * (float)hv[2]; a3 = m * (float)hv[3];
        a4 = m * (float)hv[4]; a5 = m * (float)hv[5];
        a6 = m * (float)hv[6]; a7 = m * (float)hv[7];
    }

    int e = erow + es;                             // slot stride 16
    for (; e + 16 < eend; e += 32) {               // 2 edges in flight / lane
        int2 p0 = ecw[e];
        int2 p1 = ecw[e + 16];
        f16x8 h0 = *(const f16x8*)(Hsl + (size_t)p0.x * 32 + f * 8);
        f16x8 h1 = *(const f16x8*)(Hsl + (size_t)p1.x * 32 + f * 8);
        float w0 = __int_as_float(p0.y);
        float w1 = __int_as_float(p1.y);
        a0 += w0 * (float)h0[0] + w1 * (float)h1[0];
        a1 += w0 * (float)h0[1] + w1 * (float)h1[1];
        a2 += w0 * (float)h0[2] + w1 * (float)h1[2];
        a3 += w0 * (float)h0[3] + w1 * (float)h1[3];
        a4 += w0 * (float)h0[4] + w1 * (float)h1[4];
        a5 += w0 * (float)h0[5] + w1 * (float)h1[5];
        a6 += w0 * (float)h0[6] + w1 * (float)h1[6];
        a7 += w0 * (float)h0[7] + w1 * (float)h1[7];
    }
    if (e < eend) {                                // <=1 remaining per slot
        int2 p0 = ecw[e];
        f16x8 h0 = *(const f16x8*)(Hsl + (size_t)p0.x * 32 + f * 8);
        float w0 = __int_as_float(p0.y);
        a0 += w0 * (float)h0[0];
        a1 += w0 * (float)h0[1];
        a2 += w0 * (float)h0[2];
        a3 += w0 * (float)h0[3];
        a4 += w0 * (float)h0[4];
        a5 += w0 * (float)h0[5];
        a6 += w0 * (float)h0[6];
        a7 += w0 * (float)h0[7];
    }

    // reduce across the 16 edge-slots (lane bits 2..5)
#pragma unroll
    for (int d = 4; d < 64; d <<= 1) {
        a0 += __shfl_xor(a0, d); a1 += __shfl_xor(a1, d);
        a2 += __shfl_xor(a2, d); a3 += __shfl_xor(a3, d);
        a4 += __shfl_xor(a4, d); a5 += __shfl_xor(a5, d);
        a6 += __shfl_xor(a6, d); a7 += __shfl_xor(a7, d);
    }

    if (es == 0) {
        const float* bp = bias + slice * 32 + f * 8;
        f32x4 bv0 = *(const f32x4*)(bp);
        f32x4 bv1 = *(const f32x4*)(bp + 4);
        float r0 = di * a0 + bv0.x; r0 = (r0 >= 0.f) ? r0 : av * r0;
        float r1 = di * a1 + bv0.y; r1 = (r1 >= 0.f) ? r1 : av * r1;
        float r2 = di * a2 + bv0.z; r2 = (r2 >= 0.f) ? r2 : av * r2;
        float r3 = di * a3 + bv0.w; r3 = (r3 >= 0.f) ? r3 : av * r3;
        float r4 = di * a4 + bv1.x; r4 = (r4 >= 0.f) ? r4 : av * r4;
        float r5 = di * a5 + bv1.y; r5 = (r5 >= 0.f) ? r5 : av * r5;
        float r6 = di * a6 + bv1.z; r6 = (r6 >= 0.f) ? r6 : av * r6;
        float r7 = di * a7 + bv1.w; r7 = (r7 >= 0.f) ? r7 : av * r7;
        if constexpr (sizeof(OT) == 4) {
            // final output: row-major fp32 [NN][256], never re-read -> NT
            float* p = (float*)out + (size_t)row * FF + slice * 32 + f * 8;
            f32x4 v0 = {r0, r1, r2, r3};
            f32x4 v1 = {r4, r5, r6, r7};
            __builtin_nontemporal_store(v0, (f32x4*)p);
            __builtin_nontemporal_store(v1, (f32x4*)(p + 4));
        } else {
            // intermediate: slice-major fp16 [8][NN][32] (feeds GEMM2)
            f16x8 res;
            res[0] = (_Float16)r0; res[1] = (_Float16)r1;
            res[2] = (_Float16)r2; res[3] = (_Float16)r3;
            res[4] = (_Float16)r4; res[5] = (_Float16)r5;
            res[6] = (_Float16)r6; res[7] = (_Float16)r7;
            *(f16x8*)((_Float16*)out + ((size_t)slice * NN + row) * 32 + f * 8) = res;
        }
    }
}

// ---------------------------------------------------------------------------
// Launch
// ---------------------------------------------------------------------------
extern "C" void kernel_launch(void* const* d_in, const int* in_sizes, int n_in,
                              void* d_out, int out_size, void* d_ws, size_t ws_size,
                              hipStream_t stream) {
    const float* x  = (const float*)d_in[0];
    const float* W1 = (const float*)d_in[1];
    const float* b1 = (const float*)d_in[2];
    const float* W2 = (const float*)d_in[3];
    const float* b2 = (const float*)d_in[4];
    const float* a  = (const float*)d_in[5];
    const int*   ei = (const int*)d_in[6];
    float* out = (float*)d_out;

    char* ws = (char*)d_ws;
    size_t off = 0;
    auto carve = [&](size_t bytes) -> char* {
        char* p = ws + off;
        off = (off + bytes + 255) & ~(size_t)255;
        return p;
    };
    int*      ec   = (int*)carve((size_t)NN * 4);
    int*      cnt  = (int*)carve((size_t)NN * 4);
    int*      rs   = (int*)carve((size_t)(NN + 1) * 4);
    float*    dinv = (float*)carve((size_t)NN * 4);
    int*      bsum = (int*)carve((size_t)NBLK * 4);
    int*      boff = (int*)carve((size_t)NBLK * 4);
    int2*     ecw  = (int2*)carve((size_t)EE * 8);
    _Float16* wp   = (_Float16*)carve((size_t)4 * 65536 * 2);
    _Float16* h    = (_Float16*)carve((size_t)NN * FF * 2);
    _Float16* h1   = (_Float16*)carve((size_t)NN * FF * 2);

    hipMemsetAsync(ec, 0, (size_t)NN * 4, stream);
    hipMemsetAsync(cnt, 0, (size_t)NN * 4, stream);

    count_kernel<<<(EE + 255) / 256, 256, 0, stream>>>(ei, ec);
    scan_part <<<NBLK, 256, 0, stream>>>(ec, bsum);
    scan_mid  <<<1, 256, 0, stream>>>(bsum, boff, rs);
    scan_final<<<NBLK, 256, 0, stream>>>(ec, boff, rs, dinv);
    fill_kernel<<<(EE + 255) / 256, 256, 0, stream>>>(ei, rs, cnt, dinv, ecw);
    packw_kernel<<<64, 256, 0, stream>>>(W1, W2, wp);

    // layer 1: GEMM (fp32 A, row-major) -> agg (fp16 slice-major out)
    gemm_kernel<float><<<784, 512, 0, stream>>>(x, wp, wp + 65536, h);
    agg_kernel<_Float16><<<12500 * 8, 256, 0, stream>>>(h, rs, ecw, dinv, b1, a, h1);
    // layer 2: GEMM (fp16 A, slice-major) -> agg (fp32 row-major final)
    gemm_kernel<_Float16><<<784, 512, 0, stream>>>(h1, wp + 131072, wp + 131072 + 65536, h);
    agg_kernel<float><<<12500 * 8, 256, 0, stream>>>(h, rs, ecw, dinv, b2, a, out);
}

// Round 7
// 414.564 us; speedup vs baseline: 1.2679x; 1.2679x over previous
//
#include <hip/hip_runtime.h>

// Problem constants
#define NN 50000
#define EE 800000
#define FF 256   // IN = HID = PROJ = 256
#define NBLK 196 // ceil(NN/256)

typedef float    f32x4 __attribute__((ext_vector_type(4)));
typedef float    f32x2 __attribute__((ext_vector_type(2)));
typedef _Float16 f16x8 __attribute__((ext_vector_type(8)));
typedef _Float16 f16x4 __attribute__((ext_vector_type(4)));
typedef _Float16 f16x2 __attribute__((ext_vector_type(2)));

// ---------------------------------------------------------------------------
// CSR build kernels (unchanged)
// ---------------------------------------------------------------------------

__global__ void count_kernel(const int* __restrict__ ei, int* __restrict__ ec) {
    int e = blockIdx.x * 256 + threadIdx.x;
    if (e < EE) atomicAdd(&ec[ei[EE + e]], 1);
}

__global__ __launch_bounds__(256) void scan_part(const int* __restrict__ ec,
                                                 int* __restrict__ bsum) {
    int i = blockIdx.x * 256 + threadIdx.x;
    int v = (i < NN) ? ec[i] : 0;
#pragma unroll
    for (int d = 1; d < 64; d <<= 1) v += __shfl_xor(v, d);
    __shared__ int wt[4];
    int lane = threadIdx.x & 63, wid = threadIdx.x >> 6;
    if (lane == 0) wt[wid] = v;
    __syncthreads();
    if (threadIdx.x == 0)
        bsum[blockIdx.x] = wt[0] + wt[1] + wt[2] + wt[3];
}

__global__ __launch_bounds__(256) void scan_mid(const int* __restrict__ bsum,
                                                int* __restrict__ boff,
                                                int* __restrict__ rs) {
    const int t = threadIdx.x;
    int v = (t < NBLK) ? bsum[t] : 0;
    int lane = t & 63, wid = t >> 6;
    int x = v;
#pragma unroll
    for (int d = 1; d < 64; d <<= 1) {
        int u = __shfl_up(x, d);
        if (lane >= d) x += u;
    }
    __shared__ int wt[4];
    if (lane == 63) wt[wid] = x;
    __syncthreads();
    int add = 0;
    for (int wi = 0; wi < wid; ++wi) add += wt[wi];
    x += add;                                   // inclusive scan
    if (t < NBLK) boff[t] = x - v;              // exclusive
    if (t == NBLK - 1) rs[NN] = x;              // total == EE
}

__global__ __launch_bounds__(256) void scan_final(const int* __restrict__ ec,
                                                  const int* __restrict__ boff,
                                                  int* __restrict__ rs,
                                                  float* __restrict__ dinv) {
    int i = blockIdx.x * 256 + threadIdx.x;
    int v = (i < NN) ? ec[i] : 0;
    int lane = threadIdx.x & 63, wid = threadIdx.x >> 6;
    int x = v;
#pragma unroll
    for (int d = 1; d < 64; d <<= 1) {
        int u = __shfl_up(x, d);
        if (lane >= d) x += u;
    }
    __shared__ int wt[4];
    if (lane == 63) wt[wid] = x;
    __syncthreads();
    int add = 0;
    for (int wi = 0; wi < wid; ++wi) add += wt[wi];
    x += add;                                   // block-inclusive
    if (i < NN) {
        rs[i]   = x - v + boff[blockIdx.x];     // global exclusive
        dinv[i] = rsqrtf((float)(v + 1));       // deg = edges + self-loop
    }
}

__global__ void fill_kernel(const int* __restrict__ ei, const int* __restrict__ rs,
                            int* __restrict__ cnt, const float* __restrict__ dinv,
                            int2* __restrict__ ecw) {
    int e = blockIdx.x * 256 + threadIdx.x;
    if (e >= EE) return;
    int s = ei[e];
    int d = ei[EE + e];
    int p = rs[d] + atomicAdd(&cnt[d], 1);
    ecw[p] = make_int2(s, __float_as_int(dinv[s]));
}

// ---------------------------------------------------------------------------
// W pack: swizzled LDS-image (unchanged)
// ---------------------------------------------------------------------------
__global__ void packw_kernel(const float* __restrict__ W1, const float* __restrict__ W2,
                             _Float16* __restrict__ wp) {
    int idx = blockIdx.x * 256 + threadIdx.x;   // 0..16383
    int p   = idx & 511;
    int kt  = (idx >> 9) & 7;
    int nb  = (idx >> 12) & 1;
    int L   = (idx >> 13) & 1;
    const float* W = L ? W2 : W1;
    int rs = p >> 2, cs = p & 3;
    int r  = rs ^ ((rs >> 2) & 1);
    int c  = cs ^ (r & 3);
    int n  = nb * 128 + r;
    int k0 = kt * 32 + c * 8;
    f16x8 hi, lo;
#pragma unroll
    for (int j = 0; j < 8; ++j) {
        float v = W[(size_t)(k0 + j) * 256 + n];
        _Float16 h = (_Float16)v;
        hi[j] = h;
        lo[j] = (_Float16)(v - (float)h);
    }
    size_t ch = ((size_t)((L * 2 + 0) * 2 + nb) * 8 + kt) * 4096;
    size_t cl = ((size_t)((L * 2 + 1) * 2 + nb) * 8 + kt) * 4096;
    *(f16x8*)(wp + ch + (size_t)p * 8) = hi;
    *(f16x8*)(wp + cl + (size_t)p * 8) = lo;
}

// ---------------------------------------------------------------------------
// GEMM (unchanged from round 4). Output H is SLICE-MAJOR: Hs[slice][row][32].
// ---------------------------------------------------------------------------

__device__ __forceinline__ void gll16(const void* g, void* l) {
    __builtin_amdgcn_global_load_lds(
        (const __attribute__((address_space(1))) void*)g,
        (__attribute__((address_space(3))) void*)l, 16, 0, 0);
}

template<typename AT>
__global__ __launch_bounds__(512) void gemm_kernel(
    const AT* __restrict__ X, const _Float16* __restrict__ Bhi,
    const _Float16* __restrict__ Blo, _Float16* __restrict__ H) {
    __shared__ __align__(16) _Float16 Bh[2][4096];   // 2 x 8KB
    __shared__ __align__(16) _Float16 Bl[2][4096];   // 2 x 8KB
    __shared__ __align__(16) AT       As[2][4096];   // fp32: 2x16KB, fp16: 2x8KB

    const int gid = blockIdx.x;
    const int p_  = (gid >> 4) * 8 + (gid & 7);
    const int nb  = (gid >> 3) & 1;
    if (p_ >= 391) return;

    const int tid = threadIdx.x;
    const int ln  = tid & 63;
    const int w   = tid >> 6;        // 0..7
    const int wm  = w & 1;           // 2 x 64 rows
    const int wn  = w >> 1;          // 4 x 32 cols
    const int q   = ln >> 4;         // k-group
    const int l16 = ln & 15;
    const int m0  = p_ * 128;
    const size_t bchunk = (size_t)nb * 8 * 4096;

    f32x4 acc[4][2] = {};            // [mt][nt]

    auto stage = [&](int kt, int buf) {
        int g = w * 64 + ln;                       // granule 0..511
        gll16(Bhi + bchunk + (size_t)kt * 4096 + (size_t)g * 8,
              &Bh[buf][w * 512]);
        gll16(Blo + bchunk + (size_t)kt * 4096 + (size_t)g * 8,
              &Bl[buf][w * 512]);
        if constexpr (sizeof(AT) == 4) {
#pragma unroll
            for (int pp = 0; pp < 2; ++pp) {
                int gg = pp * 512 + w * 64 + ln;    // 0..1023
                int rss = gg >> 3, cs = gg & 7;
                int c  = cs ^ (rss & 7);
                int gm = m0 + rss; if (gm > NN - 1) gm = NN - 1;
                gll16((const float*)X + (size_t)gm * FF + kt * 32 + c * 4,
                      (float*)&As[buf][0] + (size_t)(pp * 512 + w * 64) * 4);
            }
        } else {
            int rss = g >> 2, cs = g & 3;
            int r  = rss ^ ((rss >> 2) & 1);
            int c  = cs ^ (r & 3);
            int gm = m0 + r; if (gm > NN - 1) gm = NN - 1;
            gll16((const _Float16*)X + ((size_t)kt * NN + gm) * 32 + c * 8,
                  (_Float16*)&As[buf][0] + (size_t)(w * 64) * 8);
        }
    };

    auto compute = [&](int buf) {
        f16x8 af[4], bhf[2], blf[2];
#pragma unroll
        for (int mt = 0; mt < 4; ++mt) {
            int r = wm * 64 + mt * 16 + l16;
            if constexpr (sizeof(AT) == 4) {
                const float* Ab = (const float*)&As[buf][0];
                f32x4 v0 = *(const f32x4*)(Ab + (size_t)(r * 8 + ((2 * q)     ^ (r & 7))) * 4);
                f32x4 v1 = *(const f32x4*)(Ab + (size_t)(r * 8 + ((2 * q + 1) ^ (r & 7))) * 4);
                f16x8 a;
                a[0] = (_Float16)v0.x; a[1] = (_Float16)v0.y;
                a[2] = (_Float16)v0.z; a[3] = (_Float16)v0.w;
                a[4] = (_Float16)v1.x; a[5] = (_Float16)v1.y;
                a[6] = (_Float16)v1.z; a[7] = (_Float16)v1.w;
                af[mt] = a;
            } else {
                const _Float16* Ab = (const _Float16*)&As[buf][0];
                int rr = r ^ ((r >> 2) & 1);
                af[mt] = *(const f16x8*)(Ab + (size_t)(rr * 4 + (q ^ (r & 3))) * 8);
            }
        }
#pragma unroll
        for (int nt = 0; nt < 2; ++nt) {
            int r  = wn * 32 + nt * 16 + l16;
            int rr = r ^ ((r >> 2) & 1);
            int off = (rr * 4 + (q ^ (r & 3))) * 8;
            bhf[nt] = *(const f16x8*)(&Bh[buf][off]);
            blf[nt] = *(const f16x8*)(&Bl[buf][off]);
        }
#pragma unroll
        for (int mt = 0; mt < 4; ++mt)
#pragma unroll
            for (int nt = 0; nt < 2; ++nt) {
                acc[mt][nt] = __builtin_amdgcn_mfma_f32_16x16x32_f16(af[mt], bhf[nt], acc[mt][nt], 0, 0, 0);
                acc[mt][nt] = __builtin_amdgcn_mfma_f32_16x16x32_f16(af[mt], blf[nt], acc[mt][nt], 0, 0, 0);
            }
    };

    stage(0, 0);
    __syncthreads();
    int cur = 0;
#pragma unroll
    for (int kt = 0; kt < 8; ++kt) {
        if (kt < 7) stage(kt + 1, cur ^ 1);
        compute(cur);
        __syncthreads();
        cur ^= 1;
    }

    const int sl = nb * 4 + wn;
#pragma unroll
    for (int mt = 0; mt < 4; ++mt)
#pragma unroll
        for (int r4 = 0; r4 < 4; ++r4) {
            int m = m0 + wm * 64 + mt * 16 + q * 4 + r4;
            if (m < NN) {
#pragma unroll
                for (int nt = 0; nt < 2; ++nt) {
                    H[((size_t)sl * NN + m) * 32 + nt * 16 + l16] =
                        (_Float16)acc[mt][nt][r4];
                }
            }
        }
}

// ---------------------------------------------------------------------------
// Aggregation + bias + PReLU: XCD-resident slicing, lane-owns-features.
// H slice-major [8][NN][32] fp16 (3.2 MB/slice, L2-resident per XCD;
// slice = blockIdx & 7 -- round 4/6 proved FETCH 189->40 MB).
// Wave = 4 rows x (16 lanes x 2 features). Each 16-lane group walks its own
// row's edge list serially (4x unrolled -> 4 independent gather chains per
// lane); a lane accumulates its 2 features over ALL edges:
//   -> ZERO cross-lane reduction, ZERO masked lanes (round-6's 90% overhead).
// Gather = 64 B coalesced f16x2 per group; records broadcast-loaded (cached,
// adjacent rows share lines). No barriers, no LDS, no inline asm.
// ---------------------------------------------------------------------------
template<typename OT>
__global__ __launch_bounds__(256) void agg_kernel(
    const _Float16* __restrict__ Hs, const int* __restrict__ rs,
    const int2* __restrict__ ecw, const float* __restrict__ dinv,
    const float* __restrict__ bias, const float* __restrict__ a_ptr,
    OT* __restrict__ out) {
    const int slice = blockIdx.x & 7;
    const int lane  = threadIdx.x & 63;
    const int wv    = threadIdx.x >> 6;           // wave 0..3
    const int r4    = lane >> 4;                  // row within wave 0..3
    const int fl    = lane & 15;                  // feature pair 0..15
    const int row   = (blockIdx.x >> 3) * 16 + wv * 4 + r4; // <50000 (3125*16)

    const _Float16* Hsl = Hs + (size_t)slice * ((size_t)NN * 32);
    const float av = a_ptr[0];
    const float di = dinv[row];
    int e          = rs[row];
    const int eend = rs[row + 1];

    float a0, a1;
    {   // self-loop: every lane owns distinct features -> no masking
        f16x2 hv = *(const f16x2*)(Hsl + (size_t)row * 32 + fl * 2);
        a0 = di * (float)hv.x;
        a1 = di * (float)hv.y;
    }

    for (; e + 3 < eend; e += 4) {                // 4 gathers in flight / lane
        int2 q0 = ecw[e];
        int2 q1 = ecw[e + 1];
        int2 q2 = ecw[e + 2];
        int2 q3 = ecw[e + 3];
        f16x2 h0 = *(const f16x2*)(Hsl + (size_t)q0.x * 32 + fl * 2);
        f16x2 h1 = *(const f16x2*)(Hsl + (size_t)q1.x * 32 + fl * 2);
        f16x2 h2 = *(const f16x2*)(Hsl + (size_t)q2.x * 32 + fl * 2);
        f16x2 h3 = *(const f16x2*)(Hsl + (size_t)q3.x * 32 + fl * 2);
        float w0 = __int_as_float(q0.y), w1 = __int_as_float(q1.y);
        float w2 = __int_as_float(q2.y), w3 = __int_as_float(q3.y);
        a0 += w0 * (float)h0.x + w1 * (float)h1.x + w2 * (float)h2.x + w3 * (float)h3.x;
        a1 += w0 * (float)h0.y + w1 * (float)h1.y + w2 * (float)h2.y + w3 * (float)h3.y;
    }
    for (; e < eend; ++e) {
        int2 q0 = ecw[e];
        f16x2 h0 = *(const f16x2*)(Hsl + (size_t)q0.x * 32 + fl * 2);
        float w0 = __int_as_float(q0.y);
        a0 += w0 * (float)h0.x;
        a1 += w0 * (float)h0.y;
    }

    f32x2 bv = *(const f32x2*)(bias + slice * 32 + fl * 2);
    float r0 = di * a0 + bv.x; r0 = (r0 >= 0.f) ? r0 : av * r0;
    float r1 = di * a1 + bv.y; r1 = (r1 >= 0.f) ? r1 : av * r1;
    if constexpr (sizeof(OT) == 4) {
        // final output: row-major fp32 [NN][256], never re-read -> NT
        f32x2 v = {r0, r1};
        __builtin_nontemporal_store(
            v, (f32x2*)((float*)out + (size_t)row * FF + slice * 32 + fl * 2));
    } else {
        // intermediate: slice-major fp16 [8][NN][32] (feeds GEMM2; keep cached)
        f16x2 res;
        res.x = (_Float16)r0; res.y = (_Float16)r1;
        *(f16x2*)((_Float16*)out + ((size_t)slice * NN + row) * 32 + fl * 2) = res;
    }
}

// ---------------------------------------------------------------------------
// Launch
// ---------------------------------------------------------------------------
extern "C" void kernel_launch(void* const* d_in, const int* in_sizes, int n_in,
                              void* d_out, int out_size, void* d_ws, size_t ws_size,
                              hipStream_t stream) {
    const float* x  = (const float*)d_in[0];
    const float* W1 = (const float*)d_in[1];
    const float* b1 = (const float*)d_in[2];
    const float* W2 = (const float*)d_in[3];
    const float* b2 = (const float*)d_in[4];
    const float* a  = (const float*)d_in[5];
    const int*   ei = (const int*)d_in[6];
    float* out = (float*)d_out;

    char* ws = (char*)d_ws;
    size_t off = 0;
    auto carve = [&](size_t bytes) -> char* {
        char* p = ws + off;
        off = (off + bytes + 255) & ~(size_t)255;
        return p;
    };
    int*      ec   = (int*)carve((size_t)NN * 4);
    int*      cnt  = (int*)carve((size_t)NN * 4);
    int*      rs   = (int*)carve((size_t)(NN + 1) * 4);
    float*    dinv = (float*)carve((size_t)NN * 4);
    int*      bsum = (int*)carve((size_t)NBLK * 4);
    int*      boff = (int*)carve((size_t)NBLK * 4);
    int2*     ecw  = (int2*)carve((size_t)EE * 8);
    _Float16* wp   = (_Float16*)carve((size_t)4 * 65536 * 2);
    _Float16* h    = (_Float16*)carve((size_t)NN * FF * 2);
    _Float16* h1   = (_Float16*)carve((size_t)NN * FF * 2);

    hipMemsetAsync(ec, 0, (size_t)NN * 4, stream);
    hipMemsetAsync(cnt, 0, (size_t)NN * 4, stream);

    count_kernel<<<(EE + 255) / 256, 256, 0, stream>>>(ei, ec);
    scan_part <<<NBLK, 256, 0, stream>>>(ec, bsum);
    scan_mid  <<<1, 256, 0, stream>>>(bsum, boff, rs);
    scan_final<<<NBLK, 256, 0, stream>>>(ec, boff, rs, dinv);
    fill_kernel<<<(EE + 255) / 256, 256, 0, stream>>>(ei, rs, cnt, dinv, ecw);
    packw_kernel<<<64, 256, 0, stream>>>(W1, W2, wp);

    // layer 1: GEMM (fp32 A, row-major) -> agg (fp16 slice-major out)
    gemm_kernel<float><<<784, 512, 0, stream>>>(x, wp, wp + 65536, h);
    agg_kernel<_Float16><<<3125 * 8, 256, 0, stream>>>(h, rs, ecw, dinv, b1, a, h1);
    // layer 2: GEMM (fp16 A, slice-major) -> agg (fp32 row-major final)
    gemm_kernel<_Float16><<<784, 512, 0, stream>>>(h1, wp + 131072, wp + 131072 + 65536, h);
    agg_kernel<float><<<3125 * 8, 256, 0, stream>>>(h, rs, ecw, dinv, b2, a, out);
}

// Round 8
// 342.924 us; speedup vs baseline: 1.5328x; 1.2089x over previous
//
#include <hip/hip_runtime.h>

// Problem constants
#define NN 50000
#define EE 800000
#define FF 256   // IN = HID = PROJ = 256
#define NBLK 196 // ceil(NN/256)
#define GEMM_BLKS 784
#define CNT_BLKS 1563  // ceil(EE/512)

typedef float    f32x4 __attribute__((ext_vector_type(4)));
typedef _Float16 f16x8 __attribute__((ext_vector_type(8)));
typedef _Float16 f16x4 __attribute__((ext_vector_type(4)));

// ---------------------------------------------------------------------------
// CSR build kernels (count is fused into gemm1's tail blocks)
// ---------------------------------------------------------------------------

__global__ __launch_bounds__(256) void scan_part(const int* __restrict__ ec,
                                                 int* __restrict__ bsum) {
    int i = blockIdx.x * 256 + threadIdx.x;
    int v = (i < NN) ? ec[i] : 0;
#pragma unroll
    for (int d = 1; d < 64; d <<= 1) v += __shfl_xor(v, d);
    __shared__ int wt[4];
    int lane = threadIdx.x & 63, wid = threadIdx.x >> 6;
    if (lane == 0) wt[wid] = v;
    __syncthreads();
    if (threadIdx.x == 0)
        bsum[blockIdx.x] = wt[0] + wt[1] + wt[2] + wt[3];
}

__global__ __launch_bounds__(256) void scan_mid(const int* __restrict__ bsum,
                                                int* __restrict__ boff,
                                                int* __restrict__ rs) {
    const int t = threadIdx.x;
    int v = (t < NBLK) ? bsum[t] : 0;
    int lane = t & 63, wid = t >> 6;
    int x = v;
#pragma unroll
    for (int d = 1; d < 64; d <<= 1) {
        int u = __shfl_up(x, d);
        if (lane >= d) x += u;
    }
    __shared__ int wt[4];
    if (lane == 63) wt[wid] = x;
    __syncthreads();
    int add = 0;
    for (int wi = 0; wi < wid; ++wi) add += wt[wi];
    x += add;                                   // inclusive scan
    if (t < NBLK) boff[t] = x - v;              // exclusive
    if (t == NBLK - 1) rs[NN] = x;              // total == EE
}

__global__ __launch_bounds__(256) void scan_final(const int* __restrict__ ec,
                                                  const int* __restrict__ boff,
                                                  int* __restrict__ rs,
                                                  float* __restrict__ dinv) {
    int i = blockIdx.x * 256 + threadIdx.x;
    int v = (i < NN) ? ec[i] : 0;
    int lane = threadIdx.x & 63, wid = threadIdx.x >> 6;
    int x = v;
#pragma unroll
    for (int d = 1; d < 64; d <<= 1) {
        int u = __shfl_up(x, d);
        if (lane >= d) x += u;
    }
    __shared__ int wt[4];
    if (lane == 63) wt[wid] = x;
    __syncthreads();
    int add = 0;
    for (int wi = 0; wi < wid; ++wi) add += wt[wi];
    x += add;                                   // block-inclusive
    if (i < NN) {
        rs[i]   = x - v + boff[blockIdx.x];     // global exclusive
        dinv[i] = rsqrtf((float)(v + 1));       // deg = edges + self-loop
    }
}

__global__ void fill_kernel(const int* __restrict__ ei, const int* __restrict__ rs,
                            int* __restrict__ cnt, const float* __restrict__ dinv,
                            int2* __restrict__ ecw) {
    int e = blockIdx.x * 256 + threadIdx.x;
    if (e >= EE) return;
    int s = ei[e];
    int d = ei[EE + e];
    int p = rs[d] + atomicAdd(&cnt[d], 1);
    ecw[p] = make_int2(s, __float_as_int(dinv[s]));
}

// ---------------------------------------------------------------------------
// W pack: swizzled LDS-image (unchanged)
// ---------------------------------------------------------------------------
__global__ void packw_kernel(const float* __restrict__ W1, const float* __restrict__ W2,
                             _Float16* __restrict__ wp) {
    int idx = blockIdx.x * 256 + threadIdx.x;   // 0..16383
    int p   = idx & 511;
    int kt  = (idx >> 9) & 7;
    int nb  = (idx >> 12) & 1;
    int L   = (idx >> 13) & 1;
    const float* W = L ? W2 : W1;
    int rs = p >> 2, cs = p & 3;
    int r  = rs ^ ((rs >> 2) & 1);
    int c  = cs ^ (r & 3);
    int n  = nb * 128 + r;
    int k0 = kt * 32 + c * 8;
    f16x8 hi, lo;
#pragma unroll
    for (int j = 0; j < 8; ++j) {
        float v = W[(size_t)(k0 + j) * 256 + n];
        _Float16 h = (_Float16)v;
        hi[j] = h;
        lo[j] = (_Float16)(v - (float)h);
    }
    size_t ch = ((size_t)((L * 2 + 0) * 2 + nb) * 8 + kt) * 4096;
    size_t cl = ((size_t)((L * 2 + 1) * 2 + nb) * 8 + kt) * 4096;
    *(f16x8*)(wp + ch + (size_t)p * 8) = hi;
    *(f16x8*)(wp + cl + (size_t)p * 8) = lo;
}

// ---------------------------------------------------------------------------
// GEMM (round-1 proven structure, row-major H output).
// gemm1 (<float>) additionally carries count_kernel as TAIL BLOCKS
// (blockIdx >= GEMM_BLKS): count depends only on ei, gemm only on x/wp ->
// they run concurrently, removing count's serial time from the pipeline.
// ---------------------------------------------------------------------------

__device__ __forceinline__ void gll16(const void* g, void* l) {
    __builtin_amdgcn_global_load_lds(
        (const __attribute__((address_space(1))) void*)g,
        (__attribute__((address_space(3))) void*)l, 16, 0, 0);
}

template<typename AT>
__global__ __launch_bounds__(512) void gemm_kernel(
    const AT* __restrict__ X, const _Float16* __restrict__ Bhi,
    const _Float16* __restrict__ Blo, _Float16* __restrict__ H,
    const int* __restrict__ ei, int* __restrict__ ec) {
    __shared__ __align__(16) _Float16 Bh[2][4096];   // 16 KB
    __shared__ __align__(16) _Float16 Bl[2][4096];   // 16 KB
    __shared__ __align__(16) AT       As[2][4096];   // fp32: 32KB, fp16: 16KB

    if constexpr (sizeof(AT) == 4) {
        if (blockIdx.x >= GEMM_BLKS) {             // fused count tail
            int e = (blockIdx.x - GEMM_BLKS) * 512 + threadIdx.x;
            if (e < EE) atomicAdd(&ec[ei[EE + e]], 1);
            return;                                // whole block: no barriers
        }
    }

    // de-swizzle linear block id -> (pair p, member nb) with same-XCD pairing
    const int gid = blockIdx.x;
    const int p_  = (gid >> 4) * 8 + (gid & 7);
    const int nb  = (gid >> 3) & 1;
    if (p_ >= 391) return;

    const int tid = threadIdx.x;
    const int ln  = tid & 63;
    const int w   = tid >> 6;        // 0..7
    const int wm  = w & 1;           // 2 x 64 rows
    const int wn  = w >> 1;          // 4 x 32 cols
    const int q   = ln >> 4;         // k-group
    const int l16 = ln & 15;
    const int m0  = p_ * 128;
    const size_t bchunk = (size_t)nb * 8 * 4096;

    f32x4 acc[4][2] = {};            // [mt][nt]

    auto stage = [&](int kt, int buf) {
        int g = w * 64 + ln;                       // granule 0..511
        gll16(Bhi + bchunk + (size_t)kt * 4096 + (size_t)g * 8,
              &Bh[buf][w * 512]);
        gll16(Blo + bchunk + (size_t)kt * 4096 + (size_t)g * 8,
              &Bl[buf][w * 512]);
        if constexpr (sizeof(AT) == 4) {
#pragma unroll
            for (int pp = 0; pp < 2; ++pp) {
                int gg = pp * 512 + w * 64 + ln;    // 0..1023
                int rss = gg >> 3, cs = gg & 7;
                int c  = cs ^ (rss & 7);
                int gm = m0 + rss; if (gm > NN - 1) gm = NN - 1;
                gll16((const float*)X + (size_t)gm * FF + kt * 32 + c * 4,
                      (float*)&As[buf][0] + (size_t)(pp * 512 + w * 64) * 4);
            }
        } else {
            int rss = g >> 2, cs = g & 3;
            int r  = rss ^ ((rss >> 2) & 1);
            int c  = cs ^ (r & 3);
            int gm = m0 + r; if (gm > NN - 1) gm = NN - 1;
            gll16((const _Float16*)X + (size_t)gm * FF + kt * 32 + c * 8,
                  (_Float16*)&As[buf][0] + (size_t)(w * 64) * 8);
        }
    };

    auto compute = [&](int buf) {
        f16x8 af[4], bhf[2], blf[2];
#pragma unroll
        for (int mt = 0; mt < 4; ++mt) {
            int r = wm * 64 + mt * 16 + l16;
            if constexpr (sizeof(AT) == 4) {
                const float* Ab = (const float*)&As[buf][0];
                f32x4 v0 = *(const f32x4*)(Ab + (size_t)(r * 8 + ((2 * q)     ^ (r & 7))) * 4);
                f32x4 v1 = *(const f32x4*)(Ab + (size_t)(r * 8 + ((2 * q + 1) ^ (r & 7))) * 4);
                f16x8 a;
                a[0] = (_Float16)v0.x; a[1] = (_Float16)v0.y;
                a[2] = (_Float16)v0.z; a[3] = (_Float16)v0.w;
                a[4] = (_Float16)v1.x; a[5] = (_Float16)v1.y;
                a[6] = (_Float16)v1.z; a[7] = (_Float16)v1.w;
                af[mt] = a;
            } else {
                const _Float16* Ab = (const _Float16*)&As[buf][0];
                int rr = r ^ ((r >> 2) & 1);
                af[mt] = *(const f16x8*)(Ab + (size_t)(rr * 4 + (q ^ (r & 3))) * 8);
            }
        }
#pragma unroll
        for (int nt = 0; nt < 2; ++nt) {
            int r  = wn * 32 + nt * 16 + l16;
            int rr = r ^ ((r >> 2) & 1);
            int off = (rr * 4 + (q ^ (r & 3))) * 8;
            bhf[nt] = *(const f16x8*)(&Bh[buf][off]);
            blf[nt] = *(const f16x8*)(&Bl[buf][off]);
        }
#pragma unroll
        for (int mt = 0; mt < 4; ++mt)
#pragma unroll
            for (int nt = 0; nt < 2; ++nt) {
                acc[mt][nt] = __builtin_amdgcn_mfma_f32_16x16x32_f16(af[mt], bhf[nt], acc[mt][nt], 0, 0, 0);
                acc[mt][nt] = __builtin_amdgcn_mfma_f32_16x16x32_f16(af[mt], blf[nt], acc[mt][nt], 0, 0, 0);
            }
    };

    stage(0, 0);
    __syncthreads();
    int cur = 0;
#pragma unroll
    for (int kt = 0; kt < 8; ++kt) {
        if (kt < 7) stage(kt + 1, cur ^ 1);
        compute(cur);
        __syncthreads();
        cur ^= 1;
    }

    // epilogue: row-major H. C/D layout col = lane&15, row = quad*4 + reg
#pragma unroll
    for (int mt = 0; mt < 4; ++mt)
#pragma unroll
        for (int r4 = 0; r4 < 4; ++r4) {
            int m = m0 + wm * 64 + mt * 16 + q * 4 + r4;
            if (m < NN) {
#pragma unroll
                for (int nt = 0; nt < 2; ++nt) {
                    int n = nb * 128 + wn * 32 + nt * 16 + l16;
                    H[(size_t)m * FF + n] = (_Float16)acc[mt][nt][r4];
                }
            }
        }
}

// ---------------------------------------------------------------------------
// Aggregation + bias + PReLU (round-0/1 proven structure, 8-deep MLP).
// One wave per row; lane owns 4 features (8B/lane, full 512B row per gather
// instruction -- the structure that measured 64.5 us at ~3.8 TB/s).
// ---------------------------------------------------------------------------
template<typename OT>
__global__ __launch_bounds__(256) void agg_kernel(
    const _Float16* __restrict__ H, const int* __restrict__ rs,
    const int2* __restrict__ ecw, const float* __restrict__ dinv,
    const float* __restrict__ bias, const float* __restrict__ a_ptr,
    OT* __restrict__ out) {
    const int row  = blockIdx.x * 4 + (threadIdx.x >> 6);
    const int lane = threadIdx.x & 63;
    if (row >= NN) return;

    const float av = a_ptr[0];
    const float di = dinv[row];

    f16x4 hv = *(const f16x4*)(H + (size_t)row * FF + lane * 4);
    float ax = di * (float)hv.x;
    float ay = di * (float)hv.y;
    float az = di * (float)hv.z;
    float aw = di * (float)hv.w;

    int e   = rs[row];
    int end = rs[row + 1];
    for (; e + 7 < end; e += 8) {               // 8 gathers in flight
        int2 p0 = ecw[e],     p1 = ecw[e + 1], p2 = ecw[e + 2], p3 = ecw[e + 3];
        int2 p4 = ecw[e + 4], p5 = ecw[e + 5], p6 = ecw[e + 6], p7 = ecw[e + 7];
        f16x4 h0 = *(const f16x4*)(H + (size_t)p0.x * FF + lane * 4);
        f16x4 h1 = *(const f16x4*)(H + (size_t)p1.x * FF + lane * 4);
        f16x4 h2 = *(const f16x4*)(H + (size_t)p2.x * FF + lane * 4);
        f16x4 h3 = *(const f16x4*)(H + (size_t)p3.x * FF + lane * 4);
        f16x4 h4 = *(const f16x4*)(H + (size_t)p4.x * FF + lane * 4);
        f16x4 h5 = *(const f16x4*)(H + (size_t)p5.x * FF + lane * 4);
        f16x4 h6 = *(const f16x4*)(H + (size_t)p6.x * FF + lane * 4);
        f16x4 h7 = *(const f16x4*)(H + (size_t)p7.x * FF + lane * 4);
        float w0 = __int_as_float(p0.y), w1 = __int_as_float(p1.y);
        float w2 = __int_as_float(p2.y), w3 = __int_as_float(p3.y);
        float w4 = __int_as_float(p4.y), w5 = __int_as_float(p5.y);
        float w6 = __int_as_float(p6.y), w7 = __int_as_float(p7.y);
        ax += w0 * (float)h0.x + w1 * (float)h1.x + w2 * (float)h2.x + w3 * (float)h3.x
            + w4 * (float)h4.x + w5 * (float)h5.x + w6 * (float)h6.x + w7 * (float)h7.x;
        ay += w0 * (float)h0.y + w1 * (float)h1.y + w2 * (float)h2.y + w3 * (float)h3.y
            + w4 * (float)h4.y + w5 * (float)h5.y + w6 * (float)h6.y + w7 * (float)h7.y;
        az += w0 * (float)h0.z + w1 * (float)h1.z + w2 * (float)h2.z + w3 * (float)h3.z
            + w4 * (float)h4.z + w5 * (float)h5.z + w6 * (float)h6.z + w7 * (float)h7.z;
        aw += w0 * (float)h0.w + w1 * (float)h1.w + w2 * (float)h2.w + w3 * (float)h3.w
            + w4 * (float)h4.w + w5 * (float)h5.w + w6 * (float)h6.w + w7 * (float)h7.w;
    }
    for (; e + 3 < end; e += 4) {               // 4-deep remainder
        int2 p0 = ecw[e], p1 = ecw[e + 1], p2 = ecw[e + 2], p3 = ecw[e + 3];
        f16x4 h0 = *(const f16x4*)(H + (size_t)p0.x * FF + lane * 4);
        f16x4 h1 = *(const f16x4*)(H + (size_t)p1.x * FF + lane * 4);
        f16x4 h2 = *(const f16x4*)(H + (size_t)p2.x * FF + lane * 4);
        f16x4 h3 = *(const f16x4*)(H + (size_t)p3.x * FF + lane * 4);
        float w0 = __int_as_float(p0.y), w1 = __int_as_float(p1.y);
        float w2 = __int_as_float(p2.y), w3 = __int_as_float(p3.y);
        ax += w0 * (float)h0.x + w1 * (float)h1.x + w2 * (float)h2.x + w3 * (float)h3.x;
        ay += w0 * (float)h0.y + w1 * (float)h1.y + w2 * (float)h2.y + w3 * (float)h3.y;
        az += w0 * (float)h0.z + w1 * (float)h1.z + w2 * (float)h2.z + w3 * (float)h3.z;
        aw += w0 * (float)h0.w + w1 * (float)h1.w + w2 * (float)h2.w + w3 * (float)h3.w;
    }
    for (; e < end; ++e) {
        int2 p = ecw[e];
        float w0 = __int_as_float(p.y);
        f16x4 h0 = *(const f16x4*)(H + (size_t)p.x * FF + lane * 4);
        ax += w0 * (float)h0.x;
        ay += w0 * (float)h0.y;
        az += w0 * (float)h0.z;
        aw += w0 * (float)h0.w;
    }

    f32x4 bv = *(const f32x4*)(bias + lane * 4);
    float r0 = di * ax + bv.x; r0 = (r0 >= 0.f) ? r0 : av * r0;
    float r1 = di * ay + bv.y; r1 = (r1 >= 0.f) ? r1 : av * r1;
    float r2 = di * az + bv.z; r2 = (r2 >= 0.f) ? r2 : av * r2;
    float r3 = di * aw + bv.w; r3 = (r3 >= 0.f) ? r3 : av * r3;
    if constexpr (sizeof(OT) == 4) {
        f32x4 res = {r0, r1, r2, r3};
        *(f32x4*)((float*)out + (size_t)row * FF + lane * 4) = res;
    } else {
        f16x4 res;
        res.x = (_Float16)r0; res.y = (_Float16)r1;
        res.z = (_Float16)r2; res.w = (_Float16)r3;
        *(f16x4*)((_Float16*)out + (size_t)row * FF + lane * 4) = res;
    }
}

// ---------------------------------------------------------------------------
// Launch
// ---------------------------------------------------------------------------
extern "C" void kernel_launch(void* const* d_in, const int* in_sizes, int n_in,
                              void* d_out, int out_size, void* d_ws, size_t ws_size,
                              hipStream_t stream) {
    const float* x  = (const float*)d_in[0];
    const float* W1 = (const float*)d_in[1];
    const float* b1 = (const float*)d_in[2];
    const float* W2 = (const float*)d_in[3];
    const float* b2 = (const float*)d_in[4];
    const float* a  = (const float*)d_in[5];
    const int*   ei = (const int*)d_in[6];
    float* out = (float*)d_out;

    char* ws = (char*)d_ws;
    size_t off = 0;
    auto carve = [&](size_t bytes) -> char* {
        char* p = ws + off;
        off = (off + bytes + 255) & ~(size_t)255;
        return p;
    };
    int*      ec   = (int*)carve((size_t)NN * 4);
    int*      cnt  = (int*)carve((size_t)NN * 4);
    int*      rs   = (int*)carve((size_t)(NN + 1) * 4);
    float*    dinv = (float*)carve((size_t)NN * 4);
    int*      bsum = (int*)carve((size_t)NBLK * 4);
    int*      boff = (int*)carve((size_t)NBLK * 4);
    int2*     ecw  = (int2*)carve((size_t)EE * 8);
    _Float16* wp   = (_Float16*)carve((size_t)4 * 65536 * 2);
    _Float16* h    = (_Float16*)carve((size_t)NN * FF * 2);
    _Float16* h1   = (_Float16*)carve((size_t)NN * FF * 2);

    hipMemsetAsync(ec, 0, (size_t)NN * 4, stream);
    hipMemsetAsync(cnt, 0, (size_t)NN * 4, stream);

    packw_kernel<<<64, 256, 0, stream>>>(W1, W2, wp);

    // gemm1 (fp32 A) fused with count_kernel tail blocks (independent work)
    gemm_kernel<float><<<GEMM_BLKS + CNT_BLKS, 512, 0, stream>>>(
        x, wp, wp + 65536, h, ei, ec);

    scan_part <<<NBLK, 256, 0, stream>>>(ec, bsum);
    scan_mid  <<<1, 256, 0, stream>>>(bsum, boff, rs);
    scan_final<<<NBLK, 256, 0, stream>>>(ec, boff, rs, dinv);
    fill_kernel<<<(EE + 255) / 256, 256, 0, stream>>>(ei, rs, cnt, dinv, ecw);

    // layer 1 agg (fp16 out, feeds GEMM2)
    agg_kernel<_Float16><<<(NN + 3) / 4, 256, 0, stream>>>(h, rs, ecw, dinv, b1, a, h1);
    // layer 2: GEMM (fp16 A) -> agg (fp32 out, final)
    gemm_kernel<_Float16><<<GEMM_BLKS, 512, 0, stream>>>(
        h1, wp + 131072, wp + 131072 + 65536, h, nullptr, nullptr);
    agg_kernel<float><<<(NN + 3) / 4, 256, 0, stream>>>(h, rs, ecw, dinv, b2, a, out);
}

// Round 9
// 340.632 us; speedup vs baseline: 1.5431x; 1.0067x over previous
//
#include <hip/hip_runtime.h>

// Problem constants
#define NN 50000
#define EE 800000
#define FF 256   // IN = HID = PROJ = 256
#define NBLK 196 // ceil(NN/256)
#define GEMM_BLKS 784
#define FILL_BLKS 1563  // ceil(EE/512)
#define CNT_BLKS  3125  // EE/256

typedef float    f32x4 __attribute__((ext_vector_type(4)));
typedef _Float16 f16x8 __attribute__((ext_vector_type(8)));
typedef _Float16 f16x4 __attribute__((ext_vector_type(4)));

// ---------------------------------------------------------------------------
// CSR build: count is fused into packw's tail; fill into gemm1's tail.
// ---------------------------------------------------------------------------

__global__ __launch_bounds__(256) void scan_part(const int* __restrict__ ec,
                                                 int* __restrict__ bsum) {
    int i = blockIdx.x * 256 + threadIdx.x;
    int v = (i < NN) ? ec[i] : 0;
#pragma unroll
    for (int d = 1; d < 64; d <<= 1) v += __shfl_xor(v, d);
    __shared__ int wt[4];
    int lane = threadIdx.x & 63, wid = threadIdx.x >> 6;
    if (lane == 0) wt[wid] = v;
    __syncthreads();
    if (threadIdx.x == 0)
        bsum[blockIdx.x] = wt[0] + wt[1] + wt[2] + wt[3];
}

__global__ __launch_bounds__(256) void scan_mid(const int* __restrict__ bsum,
                                                int* __restrict__ boff,
                                                int* __restrict__ rs) {
    const int t = threadIdx.x;
    int v = (t < NBLK) ? bsum[t] : 0;
    int lane = t & 63, wid = t >> 6;
    int x = v;
#pragma unroll
    for (int d = 1; d < 64; d <<= 1) {
        int u = __shfl_up(x, d);
        if (lane >= d) x += u;
    }
    __shared__ int wt[4];
    if (lane == 63) wt[wid] = x;
    __syncthreads();
    int add = 0;
    for (int wi = 0; wi < wid; ++wi) add += wt[wi];
    x += add;                                   // inclusive scan
    if (t < NBLK) boff[t] = x - v;              // exclusive
    if (t == NBLK - 1) rs[NN] = x;              // total == EE
}

__global__ __launch_bounds__(256) void scan_final(const int* __restrict__ ec,
                                                  const int* __restrict__ boff,
                                                  int* __restrict__ rs,
                                                  float* __restrict__ dinv) {
    int i = blockIdx.x * 256 + threadIdx.x;
    int v = (i < NN) ? ec[i] : 0;
    int lane = threadIdx.x & 63, wid = threadIdx.x >> 6;
    int x = v;
#pragma unroll
    for (int d = 1; d < 64; d <<= 1) {
        int u = __shfl_up(x, d);
        if (lane >= d) x += u;
    }
    __shared__ int wt[4];
    if (lane == 63) wt[wid] = x;
    __syncthreads();
    int add = 0;
    for (int wi = 0; wi < wid; ++wi) add += wt[wi];
    x += add;                                   // block-inclusive
    if (i < NN) {
        rs[i]   = x - v + boff[blockIdx.x];     // global exclusive
        dinv[i] = rsqrtf((float)(v + 1));       // deg = edges + self-loop
    }
}

// ---------------------------------------------------------------------------
// W pack (swizzled LDS-image) + fused count tail blocks.
// count depends only on ei; packw only on W1/W2 -> concurrent.
// ---------------------------------------------------------------------------
__global__ void packw_kernel(const float* __restrict__ W1, const float* __restrict__ W2,
                             _Float16* __restrict__ wp,
                             const int* __restrict__ ei, int* __restrict__ ec) {
    if (blockIdx.x >= 64) {                     // fused count tail
        int e = (blockIdx.x - 64) * 256 + threadIdx.x;   // CNT_BLKS*256 == EE
        atomicAdd(&ec[ei[EE + e]], 1);
        return;                                 // whole block: no barriers
    }
    int idx = blockIdx.x * 256 + threadIdx.x;   // 0..16383
    int p   = idx & 511;
    int kt  = (idx >> 9) & 7;
    int nb  = (idx >> 12) & 1;
    int L   = (idx >> 13) & 1;
    const float* W = L ? W2 : W1;
    int rs = p >> 2, cs = p & 3;
    int r  = rs ^ ((rs >> 2) & 1);
    int c  = cs ^ (r & 3);
    int n  = nb * 128 + r;
    int k0 = kt * 32 + c * 8;
    f16x8 hi, lo;
#pragma unroll
    for (int j = 0; j < 8; ++j) {
        float v = W[(size_t)(k0 + j) * 256 + n];
        _Float16 h = (_Float16)v;
        hi[j] = h;
        lo[j] = (_Float16)(v - (float)h);
    }
    size_t ch = ((size_t)((L * 2 + 0) * 2 + nb) * 8 + kt) * 4096;
    size_t cl = ((size_t)((L * 2 + 1) * 2 + nb) * 8 + kt) * 4096;
    *(f16x8*)(wp + ch + (size_t)p * 8) = hi;
    *(f16x8*)(wp + cl + (size_t)p * 8) = lo;
}

// ---------------------------------------------------------------------------
// GEMM (round-1 proven structure, row-major H output).
// gemm1 (<float>) carries fill_kernel as TAIL BLOCKS: fill depends on
// rs/cnt/dinv (scan outputs) + ei; gemm only on x/wp -> concurrent, and
// fill's ~35 us hides entirely under gemm1.
// ---------------------------------------------------------------------------

__device__ __forceinline__ void gll16(const void* g, void* l) {
    __builtin_amdgcn_global_load_lds(
        (const __attribute__((address_space(1))) void*)g,
        (__attribute__((address_space(3))) void*)l, 16, 0, 0);
}

template<typename AT>
__global__ __launch_bounds__(512) void gemm_kernel(
    const AT* __restrict__ X, const _Float16* __restrict__ Bhi,
    const _Float16* __restrict__ Blo, _Float16* __restrict__ H,
    const int* __restrict__ ei, const int* __restrict__ rs,
    int* __restrict__ cnt, const float* __restrict__ dinv,
    int2* __restrict__ ecw) {
    __shared__ __align__(16) _Float16 Bh[2][4096];   // 16 KB
    __shared__ __align__(16) _Float16 Bl[2][4096];   // 16 KB
    __shared__ __align__(16) AT       As[2][4096];   // fp32: 32KB, fp16: 16KB

    if constexpr (sizeof(AT) == 4) {
        if (blockIdx.x >= GEMM_BLKS) {             // fused fill tail
            int e = (blockIdx.x - GEMM_BLKS) * 512 + threadIdx.x;
            if (e < EE) {
                int s = ei[e];
                int d = ei[EE + e];
                int p = rs[d] + atomicAdd(&cnt[d], 1);
                ecw[p] = make_int2(s, __float_as_int(dinv[s]));
            }
            return;                                // whole block: no barriers
        }
    }

    // de-swizzle linear block id -> (pair p, member nb) with same-XCD pairing
    const int gid = blockIdx.x;
    const int p_  = (gid >> 4) * 8 + (gid & 7);
    const int nb  = (gid >> 3) & 1;
    if (p_ >= 391) return;

    const int tid = threadIdx.x;
    const int ln  = tid & 63;
    const int w   = tid >> 6;        // 0..7
    const int wm  = w & 1;           // 2 x 64 rows
    const int wn  = w >> 1;          // 4 x 32 cols
    const int q   = ln >> 4;         // k-group
    const int l16 = ln & 15;
    const int m0  = p_ * 128;
    const size_t bchunk = (size_t)nb * 8 * 4096;

    f32x4 acc[4][2] = {};            // [mt][nt]

    auto stage = [&](int kt, int buf) {
        int g = w * 64 + ln;                       // granule 0..511
        gll16(Bhi + bchunk + (size_t)kt * 4096 + (size_t)g * 8,
              &Bh[buf][w * 512]);
        gll16(Blo + bchunk + (size_t)kt * 4096 + (size_t)g * 8,
              &Bl[buf][w * 512]);
        if constexpr (sizeof(AT) == 4) {
#pragma unroll
            for (int pp = 0; pp < 2; ++pp) {
                int gg = pp * 512 + w * 64 + ln;    // 0..1023
                int rss = gg >> 3, cs = gg & 7;
                int c  = cs ^ (rss & 7);
                int gm = m0 + rss; if (gm > NN - 1) gm = NN - 1;
                gll16((const float*)X + (size_t)gm * FF + kt * 32 + c * 4,
                      (float*)&As[buf][0] + (size_t)(pp * 512 + w * 64) * 4);
            }
        } else {
            int rss = g >> 2, cs = g & 3;
            int r  = rss ^ ((rss >> 2) & 1);
            int c  = cs ^ (r & 3);
            int gm = m0 + r; if (gm > NN - 1) gm = NN - 1;
            gll16((const _Float16*)X + (size_t)gm * FF + kt * 32 + c * 8,
                  (_Float16*)&As[buf][0] + (size_t)(w * 64) * 8);
        }
    };

    auto compute = [&](int buf) {
        f16x8 af[4], bhf[2], blf[2];
#pragma unroll
        for (int mt = 0; mt < 4; ++mt) {
            int r = wm * 64 + mt * 16 + l16;
            if constexpr (sizeof(AT) == 4) {
                const float* Ab = (const float*)&As[buf][0];
                f32x4 v0 = *(const f32x4*)(Ab + (size_t)(r * 8 + ((2 * q)     ^ (r & 7))) * 4);
                f32x4 v1 = *(const f32x4*)(Ab + (size_t)(r * 8 + ((2 * q + 1) ^ (r & 7))) * 4);
                f16x8 a;
                a[0] = (_Float16)v0.x; a[1] = (_Float16)v0.y;
                a[2] = (_Float16)v0.z; a[3] = (_Float16)v0.w;
                a[4] = (_Float16)v1.x; a[5] = (_Float16)v1.y;
                a[6] = (_Float16)v1.z; a[7] = (_Float16)v1.w;
                af[mt] = a;
            } else {
                const _Float16* Ab = (const _Float16*)&As[buf][0];
                int rr = r ^ ((r >> 2) & 1);
                af[mt] = *(const f16x8*)(Ab + (size_t)(rr * 4 + (q ^ (r & 3))) * 8);
            }
        }
#pragma unroll
        for (int nt = 0; nt < 2; ++nt) {
            int r  = wn * 32 + nt * 16 + l16;
            int rr = r ^ ((r >> 2) & 1);
            int off = (rr * 4 + (q ^ (r & 3))) * 8;
            bhf[nt] = *(const f16x8*)(&Bh[buf][off]);
            blf[nt] = *(const f16x8*)(&Bl[buf][off]);
        }
#pragma unroll
        for (int mt = 0; mt < 4; ++mt)
#pragma unroll
            for (int nt = 0; nt < 2; ++nt) {
                acc[mt][nt] = __builtin_amdgcn_mfma_f32_16x16x32_f16(af[mt], bhf[nt], acc[mt][nt], 0, 0, 0);
                acc[mt][nt] = __builtin_amdgcn_mfma_f32_16x16x32_f16(af[mt], blf[nt], acc[mt][nt], 0, 0, 0);
            }
    };

    stage(0, 0);
    __syncthreads();
    int cur = 0;
#pragma unroll
    for (int kt = 0; kt < 8; ++kt) {
        if (kt < 7) stage(kt + 1, cur ^ 1);
        compute(cur);
        __syncthreads();
        cur ^= 1;
    }

    // epilogue: row-major H. C/D layout col = lane&15, row = quad*4 + reg
#pragma unroll
    for (int mt = 0; mt < 4; ++mt)
#pragma unroll
        for (int r4 = 0; r4 < 4; ++r4) {
            int m = m0 + wm * 64 + mt * 16 + q * 4 + r4;
            if (m < NN) {
#pragma unroll
                for (int nt = 0; nt < 2; ++nt) {
                    int n = nb * 128 + wn * 32 + nt * 16 + l16;
                    H[(size_t)m * FF + n] = (_Float16)acc[mt][nt][r4];
                }
            }
        }
}

// ---------------------------------------------------------------------------
// Aggregation + bias + PReLU (proven structure, 8-deep MLP -- at the
// random-gather service ceiling, 63 us / 48% HBM; do not touch).
// ---------------------------------------------------------------------------
template<typename OT>
__global__ __launch_bounds__(256) void agg_kernel(
    const _Float16* __restrict__ H, const int* __restrict__ rs,
    const int2* __restrict__ ecw, const float* __restrict__ dinv,
    const float* __restrict__ bias, const float* __restrict__ a_ptr,
    OT* __restrict__ out) {
    const int row  = blockIdx.x * 4 + (threadIdx.x >> 6);
    const int lane = threadIdx.x & 63;
    if (row >= NN) return;

    const float av = a_ptr[0];
    const float di = dinv[row];

    f16x4 hv = *(const f16x4*)(H + (size_t)row * FF + lane * 4);
    float ax = di * (float)hv.x;
    float ay = di * (float)hv.y;
    float az = di * (float)hv.z;
    float aw = di * (float)hv.w;

    int e   = rs[row];
    int end = rs[row + 1];
    for (; e + 7 < end; e += 8) {               // 8 gathers in flight
        int2 p0 = ecw[e],     p1 = ecw[e + 1], p2 = ecw[e + 2], p3 = ecw[e + 3];
        int2 p4 = ecw[e + 4], p5 = ecw[e + 5], p6 = ecw[e + 6], p7 = ecw[e + 7];
        f16x4 h0 = *(const f16x4*)(H + (size_t)p0.x * FF + lane * 4);
        f16x4 h1 = *(const f16x4*)(H + (size_t)p1.x * FF + lane * 4);
        f16x4 h2 = *(const f16x4*)(H + (size_t)p2.x * FF + lane * 4);
        f16x4 h3 = *(const f16x4*)(H + (size_t)p3.x * FF + lane * 4);
        f16x4 h4 = *(const f16x4*)(H + (size_t)p4.x * FF + lane * 4);
        f16x4 h5 = *(const f16x4*)(H + (size_t)p5.x * FF + lane * 4);
        f16x4 h6 = *(const f16x4*)(H + (size_t)p6.x * FF + lane * 4);
        f16x4 h7 = *(const f16x4*)(H + (size_t)p7.x * FF + lane * 4);
        float w0 = __int_as_float(p0.y), w1 = __int_as_float(p1.y);
        float w2 = __int_as_float(p2.y), w3 = __int_as_float(p3.y);
        float w4 = __int_as_float(p4.y), w5 = __int_as_float(p5.y);
        float w6 = __int_as_float(p6.y), w7 = __int_as_float(p7.y);
        ax += w0 * (float)h0.x + w1 * (float)h1.x + w2 * (float)h2.x + w3 * (float)h3.x
            + w4 * (float)h4.x + w5 * (float)h5.x + w6 * (float)h6.x + w7 * (float)h7.x;
        ay += w0 * (float)h0.y + w1 * (float)h1.y + w2 * (float)h2.y + w3 * (float)h3.y
            + w4 * (float)h4.y + w5 * (float)h5.y + w6 * (float)h6.y + w7 * (float)h7.y;
        az += w0 * (float)h0.z + w1 * (float)h1.z + w2 * (float)h2.z + w3 * (float)h3.z
            + w4 * (float)h4.z + w5 * (float)h5.z + w6 * (float)h6.z + w7 * (float)h7.z;
        aw += w0 * (float)h0.w + w1 * (float)h1.w + w2 * (float)h2.w + w3 * (float)h3.w
            + w4 * (float)h4.w + w5 * (float)h5.w + w6 * (float)h6.w + w7 * (float)h7.w;
    }
    for (; e + 3 < end; e += 4) {               // 4-deep remainder
        int2 p0 = ecw[e], p1 = ecw[e + 1], p2 = ecw[e + 2], p3 = ecw[e + 3];
        f16x4 h0 = *(const f16x4*)(H + (size_t)p0.x * FF + lane * 4);
        f16x4 h1 = *(const f16x4*)(H + (size_t)p1.x * FF + lane * 4);
        f16x4 h2 = *(const f16x4*)(H + (size_t)p2.x * FF + lane * 4);
        f16x4 h3 = *(const f16x4*)(H + (size_t)p3.x * FF + lane * 4);
        float w0 = __int_as_float(p0.y), w1 = __int_as_float(p1.y);
        float w2 = __int_as_float(p2.y), w3 = __int_as_float(p3.y);
        ax += w0 * (float)h0.x + w1 * (float)h1.x + w2 * (float)h2.x + w3 * (float)h3.x;
        ay += w0 * (float)h0.y + w1 * (float)h1.y + w2 * (float)h2.y + w3 * (float)h3.y;
        az += w0 * (float)h0.z + w1 * (float)h1.z + w2 * (float)h2.z + w3 * (float)h3.z;
        aw += w0 * (float)h0.w + w1 * (float)h1.w + w2 * (float)h2.w + w3 * (float)h3.w;
    }
    for (; e < end; ++e) {
        int2 p = ecw[e];
        float w0 = __int_as_float(p.y);
        f16x4 h0 = *(const f16x4*)(H + (size_t)p.x * FF + lane * 4);
        ax += w0 * (float)h0.x;
        ay += w0 * (float)h0.y;
        az += w0 * (float)h0.z;
        aw += w0 * (float)h0.w;
    }

    f32x4 bv = *(const f32x4*)(bias + lane * 4);
    float r0 = di * ax + bv.x; r0 = (r0 >= 0.f) ? r0 : av * r0;
    float r1 = di * ay + bv.y; r1 = (r1 >= 0.f) ? r1 : av * r1;
    float r2 = di * az + bv.z; r2 = (r2 >= 0.f) ? r2 : av * r2;
    float r3 = di * aw + bv.w; r3 = (r3 >= 0.f) ? r3 : av * r3;
    if constexpr (sizeof(OT) == 4) {
        f32x4 res = {r0, r1, r2, r3};
        *(f32x4*)((float*)out + (size_t)row * FF + lane * 4) = res;
    } else {
        f16x4 res;
        res.x = (_Float16)r0; res.y = (_Float16)r1;
        res.z = (_Float16)r2; res.w = (_Float16)r3;
        *(f16x4*)((_Float16*)out + (size_t)row * FF + lane * 4) = res;
    }
}

// ---------------------------------------------------------------------------
// Launch
// ---------------------------------------------------------------------------
extern "C" void kernel_launch(void* const* d_in, const int* in_sizes, int n_in,
                              void* d_out, int out_size, void* d_ws, size_t ws_size,
                              hipStream_t stream) {
    const float* x  = (const float*)d_in[0];
    const float* W1 = (const float*)d_in[1];
    const float* b1 = (const float*)d_in[2];
    const float* W2 = (const float*)d_in[3];
    const float* b2 = (const float*)d_in[4];
    const float* a  = (const float*)d_in[5];
    const int*   ei = (const int*)d_in[6];
    float* out = (float*)d_out;

    char* ws = (char*)d_ws;
    size_t off = 0;
    auto carve = [&](size_t bytes) -> char* {
        char* p = ws + off;
        off = (off + bytes + 255) & ~(size_t)255;
        return p;
    };
    int*      ec   = (int*)carve((size_t)NN * 4);
    int*      cnt  = (int*)carve((size_t)NN * 4);
    int*      rs   = (int*)carve((size_t)(NN + 1) * 4);
    float*    dinv = (float*)carve((size_t)NN * 4);
    int*      bsum = (int*)carve((size_t)NBLK * 4);
    int*      boff = (int*)carve((size_t)NBLK * 4);
    int2*     ecw  = (int2*)carve((size_t)EE * 8);
    _Float16* wp   = (_Float16*)carve((size_t)4 * 65536 * 2);
    _Float16* h    = (_Float16*)carve((size_t)NN * FF * 2);
    _Float16* h1   = (_Float16*)carve((size_t)NN * FF * 2);

    hipMemsetAsync(ec, 0, (size_t)NN * 4, stream);
    hipMemsetAsync(cnt, 0, (size_t)NN * 4, stream);

    // packw (64 blocks) fused with count (3125 tail blocks) -- independent
    packw_kernel<<<64 + CNT_BLKS, 256, 0, stream>>>(W1, W2, wp, ei, ec);

    scan_part <<<NBLK, 256, 0, stream>>>(ec, bsum);
    scan_mid  <<<1, 256, 0, stream>>>(bsum, boff, rs);
    scan_final<<<NBLK, 256, 0, stream>>>(ec, boff, rs, dinv);

    // gemm1 (fp32 A) fused with fill tail blocks (independent work)
    gemm_kernel<float><<<GEMM_BLKS + FILL_BLKS, 512, 0, stream>>>(
        x, wp, wp + 65536, h, ei, rs, cnt, dinv, ecw);

    // layer 1 agg (fp16 out, feeds GEMM2)
    agg_kernel<_Float16><<<(NN + 3) / 4, 256, 0, stream>>>(h, rs, ecw, dinv, b1, a, h1);
    // layer 2: GEMM (fp16 A) -> agg (fp32 out, final)
    gemm_kernel<_Float16><<<GEMM_BLKS, 512, 0, stream>>>(
        h1, wp + 131072, wp + 131072 + 65536, h, nullptr, nullptr, nullptr, nullptr, nullptr);
    agg_kernel<float><<<(NN + 3) / 4, 256, 0, stream>>>(h, rs, ecw, dinv, b2, a, out);
}